// Round 7
// baseline (437.678 us; speedup 1.0000x reference)
//
#include <hip/hip_runtime.h>

// LNSNet forward, R6: TWO kernels.
//  k1: conv1 sliding-row (packed fp32) + weight prep + barrier-counter zeroing
//  k2: persistent fused conv2(MFMA)+pool -> [grid barrier] -> fc1(MFMA split-K)
//      -> [grid barrier] -> fc1-reduce+bias+relu+fc2.
//      768 blocks x 256 thr, __launch_bounds__(256,3): 3 blocks/CU needed,
//      co-residency margin 3x -> safe device-scope spin barriers.

#define B 512
#define POS 676            // 26*26 pooled conv1 spatial
#define ICP 36             // padded ic stride in conv2 LDS
#define P2SZ (64*12*12)    // 9216

typedef unsigned short ushort_t;
typedef ushort_t ushort4v __attribute__((ext_vector_type(4)));
typedef short s16x8 __attribute__((ext_vector_type(8)));
typedef float f32x4 __attribute__((ext_vector_type(4)));
typedef float f32x2 __attribute__((ext_vector_type(2)));

__device__ __forceinline__ ushort_t f2bf(float f) {
    union { float f; unsigned u; } a; a.f = f;
    unsigned r = a.u + 0x7FFFu + ((a.u >> 16) & 1u);   // RNE
    return (ushort_t)(r >> 16);
}
__device__ __forceinline__ float bf2f(ushort_t u) {
    union { unsigned u; float f; } a; a.u = ((unsigned)u) << 16;
    return a.f;
}

#define N_WR (64 * 9 * 32)          // 18432
#define N_WF (128 * 9216)           // 1179648
#define CONV1_BLOCKS 1664           // 512*26*32 / 256
#define PREP_BLOCKS  4680           // (N_WR+N_WF)/256
#define FUSED_BLOCKS 768

// ---------------- k1: conv1 sliding-row (packed fp32) + weight prep ----------------
__global__ __launch_bounds__(256) void conv1_prep(const float* __restrict__ x,
                                                  const float* __restrict__ w,
                                                  const float* __restrict__ bias,
                                                  const float* __restrict__ c2w,
                                                  const float* __restrict__ f1w,
                                                  ushort_t* __restrict__ out,
                                                  ushort_t* __restrict__ wr,
                                                  ushort_t* __restrict__ wfb,
                                                  unsigned* __restrict__ barrier_ctr) {
    int blk = blockIdx.x;
    if (blk >= CONV1_BLOCKS) {
        if (blk == CONV1_BLOCKS && threadIdx.x < 2) barrier_ctr[threadIdx.x] = 0;
        int t = (blk - CONV1_BLOCKS) * 256 + threadIdx.x;
        if (t < N_WR) {
            int ic  = t & 31;
            int tap = (t >> 5) % 9;
            int oc  = t / 288;
            wr[t] = f2bf(c2w[oc * 288 + ic * 9 + tap]);
        } else if (t < N_WR + N_WF) {
            int i = t - N_WR;
            wfb[i] = f2bf(f1w[i]);
        }
        return;
    }
    int t = blk * 256 + threadIdx.x;
    int ic = t & 31;
    int r  = t >> 5;          // b*26 + py
    int py = r % 26;
    int b  = r / 26;

    const float* wp = w + ic * 9;
    float w00 = wp[0], w01 = wp[1], w02 = wp[2];
    float w10 = wp[3], w11 = wp[4], w12 = wp[5];
    float w20 = wp[6], w21 = wp[7], w22 = wp[8];
    float bv = bias[ic];

    const float* xr = x + b * (54 * 54) + (2 * py) * 54;
    ushort_t* po = out + ((size_t)b * POS + py * 26) * 32 + ic;

    f32x2 p[4], q[4];
#pragma unroll
    for (int rr = 0; rr < 4; ++rr) p[rr] = *reinterpret_cast<const f32x2*>(xr + rr * 54);
#pragma unroll
    for (int rr = 0; rr < 4; ++rr) q[rr] = *reinterpret_cast<const f32x2*>(xr + rr * 54 + 2);

#pragma unroll
    for (int px = 0; px < 26; ++px) {
        f32x2 mid[4];
#pragma unroll
        for (int rr = 0; rr < 4; ++rr) mid[rr] = (f32x2){p[rr].y, q[rr].x};

        f32x2 s0 = p[0] * (f32x2)w00 + mid[0] * (f32x2)w01 + q[0] * (f32x2)w02
                 + p[1] * (f32x2)w10 + mid[1] * (f32x2)w11 + q[1] * (f32x2)w12
                 + p[2] * (f32x2)w20 + mid[2] * (f32x2)w21 + q[2] * (f32x2)w22;
        f32x2 s1 = p[1] * (f32x2)w00 + mid[1] * (f32x2)w01 + q[1] * (f32x2)w02
                 + p[2] * (f32x2)w10 + mid[2] * (f32x2)w11 + q[2] * (f32x2)w12
                 + p[3] * (f32x2)w20 + mid[3] * (f32x2)w21 + q[3] * (f32x2)w22;

        float m = fmaxf(fmaxf(s0.x, s0.y), fmaxf(s1.x, s1.y));
        po[px * 32] = f2bf(fmaxf(m + bv, 0.0f));
        if (px < 25) {
#pragma unroll
            for (int rr = 0; rr < 4; ++rr) {
                p[rr] = q[rr];
                q[rr] = *reinterpret_cast<const f32x2*>(xr + rr * 54 + 2 * px + 4);
            }
        }
    }
}

// ---------------- device-scope grid barrier (all FUSED_BLOCKS co-resident) ----------------
__device__ __forceinline__ void grid_barrier(unsigned* ctr, unsigned target) {
    __threadfence();          // release this thread's prior writes device-wide
    __syncthreads();          // all block threads' fences done before arrival
    if (threadIdx.x == 0) {
        atomicAdd(ctr, 1u);   // device-scope by default
        while (__hip_atomic_load(ctr, __ATOMIC_RELAXED, __HIP_MEMORY_SCOPE_AGENT) < target)
            __builtin_amdgcn_s_sleep(8);
        __threadfence();      // acquire
    }
    __syncthreads();
}

// ---------------- k2: fused conv2 -> fc1 -> fc2 ----------------
__global__ __launch_bounds__(256, 3) void fused_net(const ushort_t* __restrict__ p1,
                                                    const ushort_t* __restrict__ wr,
                                                    const float* __restrict__ c2b,
                                                    const ushort_t* __restrict__ wfb,
                                                    const float* __restrict__ b1,
                                                    const float* __restrict__ w2,
                                                    const float* __restrict__ b2,
                                                    ushort_t* __restrict__ pool2,
                                                    float* __restrict__ Cpart,
                                                    float* __restrict__ out,
                                                    unsigned* __restrict__ barrier_ctr) {
    __shared__ ushort_t lds[260 * ICP];   // 18,720 B
    int blk = blockIdx.x;
    int tid = threadIdx.x;
    int lane = tid & 63, wid = tid >> 6;
    int quad = lane >> 4, lr = lane & 15;

    // ======== phase A: conv2 MFMA + relu + pool, 2 chunks/block ========
#pragma unroll 1
    for (int cc = 0; cc < 2; ++cc) {
        int ch = blk * 2 + cc;            // 0..1535
        int b = ch / 3, c = ch % 3;

        const ushort_t* src = p1 + ((size_t)b * POS + 8 * c * 26) * 32;
        for (int t = tid; t < 260 * 8; t += 256) {
            int pos = t >> 3, off = (t & 7) * 4;
            ushort4v v = *reinterpret_cast<const ushort4v*>(src + pos * 32 + off);
            *reinterpret_cast<ushort4v*>(&lds[pos * ICP + off]) = v;
        }
        __syncthreads();

        int ebase[3];
#pragma unroll
        for (int t = 0; t < 3; ++t) {
            int m  = t * 16 + lr;
            int yl = m / 24;
            int xx = m - yl * 24;
            ebase[t] = ((2 * wid + yl) * 26 + xx) * ICP + quad * 8;
        }

        f32x4 acc[3][4];
#pragma unroll
        for (int t = 0; t < 3; ++t)
#pragma unroll
            for (int n = 0; n < 4; ++n) acc[t][n] = (f32x4){0.f, 0.f, 0.f, 0.f};

        const ushort_t* wb = wr + (size_t)lr * 288 + quad * 8;

#pragma unroll
        for (int tap = 0; tap < 9; ++tap) {
            int ky = tap / 3, kx = tap % 3;
            int koff = (ky * 26 + kx) * ICP;
            s16x8 a[3];
#pragma unroll
            for (int t = 0; t < 3; ++t) {
                union { ushort4v s[2]; s16x8 v; } u;
                u.s[0] = *reinterpret_cast<const ushort4v*>(&lds[ebase[t] + koff]);
                u.s[1] = *reinterpret_cast<const ushort4v*>(&lds[ebase[t] + koff + 4]);
                a[t] = u.v;
            }
            s16x8 bf[4];
#pragma unroll
            for (int n = 0; n < 4; ++n)
                bf[n] = *reinterpret_cast<const s16x8*>(wb + n * 4608 + tap * 32);
#pragma unroll
            for (int t = 0; t < 3; ++t)
#pragma unroll
                for (int n = 0; n < 4; ++n)
                    acc[t][n] = __builtin_amdgcn_mfma_f32_16x16x32_bf16(a[t], bf[n], acc[t][n], 0, 0, 0);
        }
        __syncthreads();   // image LDS dead; reuse as per-wave pooling scratch

        ushort_t* scr = lds + wid * 1536;
#pragma unroll
        for (int t = 0; t < 3; ++t)
#pragma unroll
            for (int n = 0; n < 4; ++n) {
                int oc = n * 16 + lr;
                int i0 = t * 8 + quad * 2;
                float v0 = fmaxf(acc[t][n][0], acc[t][n][1]);
                float v1 = fmaxf(acc[t][n][2], acc[t][n][3]);
                union { ushort_t u2[2]; unsigned w; } pk;
                pk.u2[0] = f2bf(v0); pk.u2[1] = f2bf(v1);
                *reinterpret_cast<unsigned*>(&scr[oc * 24 + i0]) = pk.w;
            }
        // per-wave scratch: only this wave reads it back
        int oc = lane;
        const ushort_t* row = scr + oc * 24;
        float bv = c2b[oc];
        int py = c * 4 + wid;
        ushort_t outv[12];
#pragma unroll
        for (int px = 0; px < 12; ++px) {
            float r0 = bf2f(row[px]);
            float r1 = bf2f(row[px + 12]);
            outv[px] = f2bf(fmaxf(fmaxf(r0, r1) + bv, 0.0f));
        }
        ushort_t* po = pool2 + ((size_t)(b * 64 + oc) * 144 + py * 12);
#pragma unroll
        for (int q = 0; q < 3; ++q)
            *reinterpret_cast<ushort4v*>(po + q * 4) =
                (ushort4v){outv[q*4+0], outv[q*4+1], outv[q*4+2], outv[q*4+3]};
        __syncthreads();   // protect LDS before restage
    }

    grid_barrier(&barrier_ctr[0], FUSED_BLOCKS);

    // ======== phase B: fc1 bf16 MFMA split-K (2048 wave-jobs on first 512 blocks) ========
    if (blk < 512) {
        int job = blk * 4 + wid;          // 0..2047
        int nt = job & 3;
        int ks = (job >> 2) & 31;
        int mt = job >> 7;                // 0..15

        int m0 = mt * 32;
        int n0 = nt * 32;
        int k0 = ks * 288 + quad * 8;
        const ushort_t* a0 = pool2 + (size_t)(m0 + lr) * 9216 + k0;
        const ushort_t* a1 = a0 + (size_t)16 * 9216;
        const ushort_t* b0 = wfb + (size_t)(n0 + lr) * 9216 + k0;
        const ushort_t* bq1 = b0 + (size_t)16 * 9216;

        f32x4 facc[2][2];
#pragma unroll
        for (int i = 0; i < 2; ++i)
#pragma unroll
            for (int j = 0; j < 2; ++j) facc[i][j] = (f32x4){0.f, 0.f, 0.f, 0.f};

#pragma unroll
        for (int kk = 0; kk < 9; ++kk) {
            s16x8 av0 = *reinterpret_cast<const s16x8*>(a0 + kk * 32);
            s16x8 av1 = *reinterpret_cast<const s16x8*>(a1 + kk * 32);
            s16x8 bv0 = *reinterpret_cast<const s16x8*>(b0 + kk * 32);
            s16x8 bv1 = *reinterpret_cast<const s16x8*>(bq1 + kk * 32);
            facc[0][0] = __builtin_amdgcn_mfma_f32_16x16x32_bf16(av0, bv0, facc[0][0], 0, 0, 0);
            facc[0][1] = __builtin_amdgcn_mfma_f32_16x16x32_bf16(av0, bv1, facc[0][1], 0, 0, 0);
            facc[1][0] = __builtin_amdgcn_mfma_f32_16x16x32_bf16(av1, bv0, facc[1][0], 0, 0, 0);
            facc[1][1] = __builtin_amdgcn_mfma_f32_16x16x32_bf16(av1, bv1, facc[1][1], 0, 0, 0);
        }

        float* cp = Cpart + (size_t)ks * (512 * 128);
#pragma unroll
        for (int i = 0; i < 2; ++i) {
            int crow = m0 + i * 16 + quad * 4;
#pragma unroll
            for (int j = 0; j < 2; ++j) {
                int col = n0 + j * 16 + lr;
#pragma unroll
                for (int r = 0; r < 4; ++r)
                    cp[(size_t)(crow + r) * 128 + col] = facc[i][j][r];
            }
        }
    }

    grid_barrier(&barrier_ctr[1], FUSED_BLOCKS);

    // ======== phase C: fc1 reduce + bias + relu + fc2 (first 512 blocks) ========
    if (blk < 512) {
        float* hsh = reinterpret_cast<float*>(lds);
        int b = blk, k = tid;
        if (k < 128) {
            float s = 0.f;
#pragma unroll
            for (int ks = 0; ks < 32; ++ks) s += Cpart[(size_t)ks * (512 * 128) + b * 128 + k];
            hsh[k] = fmaxf(s + b1[k], 0.0f);
        }
        __syncthreads();
        if (k < 10) {
            const float* wp = w2 + k * 128;
            float acc = 0.f;
#pragma unroll 8
            for (int j = 0; j < 128; ++j) acc += hsh[j] * wp[j];
            out[b * 10 + k] = acc + b2[k];
        }
    }
}

extern "C" void kernel_launch(void* const* d_in, const int* in_sizes, int n_in,
                              void* d_out, int out_size, void* d_ws, size_t ws_size,
                              hipStream_t stream) {
    const float* x       = (const float*)d_in[0];
    const float* conv1_w = (const float*)d_in[1];
    const float* conv1_b = (const float*)d_in[2];
    const float* conv2_w = (const float*)d_in[3];
    const float* conv2_b = (const float*)d_in[4];
    const float* fc1_w   = (const float*)d_in[5];
    const float* fc1_b   = (const float*)d_in[6];
    const float* fc2_w   = (const float*)d_in[7];
    const float* fc2_b   = (const float*)d_in[8];
    float* out = (float*)d_out;

    char* ws = (char*)d_ws;
    ushort_t* pool1 = (ushort_t*)ws;                         // 22.1 MB
    ws += (size_t)B * POS * 32 * sizeof(ushort_t);
    ushort_t* wr = (ushort_t*)ws;                            // 36 KB
    ws += N_WR * sizeof(ushort_t) + 128;
    ushort_t* wfb = (ushort_t*)ws;                           // 2.36 MB
    ws += N_WF * sizeof(ushort_t) + 128;
    ushort_t* pool2b = (ushort_t*)ws;                        // 9.44 MB
    ws += (size_t)B * P2SZ * sizeof(ushort_t) + 128;
    float* Cpart = (float*)ws;                               // 8.39 MB
    ws += (size_t)32 * 512 * 128 * sizeof(float) + 128;
    unsigned* barrier_ctr = (unsigned*)ws;                   // 2 x u32 (zeroed by k1)
    ws += 256;

    {   // k1: conv1 + weight prep + barrier-counter zero
        conv1_prep<<<CONV1_BLOCKS + PREP_BLOCKS, 256, 0, stream>>>(
            x, conv1_w, conv1_b, conv2_w, fc1_w, pool1, wr, wfb, barrier_ctr);
    }
    {   // k2: fused conv2 -> fc1 -> fc2 (persistent, 768 co-resident blocks)
        fused_net<<<FUSED_BLOCKS, 256, 0, stream>>>(
            pool1, wr, conv2_b, wfb, fc1_b, fc2_w, fc2_b, pool2b, Cpart, out, barrier_ctr);
    }
}

// Round 8
// 131.247 us; speedup vs baseline: 3.3348x; 3.3348x over previous
//
#include <hip/hip_runtime.h>

// LNSNet forward, R7 (revert R6 fusion; R5 + surgical fixes):
//  k1: conv1 sliding-row packed fp32, 13-px half-rows (2x waves) + weight prep
//  k2: conv2 bf16 MFMA, 3 blocks/image; epilogue stores pool2 CHANNELS-LAST
//      [b][pos][oc] bf16 -> 128B contiguous wave stores (R6 showed 4.5x write
//      amplification from the old 8B-scatter epilogue)
//  k3: fc1 bf16 MFMA 32x32-tile waves over permuted K (pos*64+oc), 2048 waves
//  k4: fc1 reduce + bias + relu + fc2
// NO device-scope fences anywhere (R6 lesson: they flush non-coherent XCD L2s).

#define B 512
#define POS 676            // 26*26 pooled conv1 spatial
#define ICP 36             // padded ic stride in conv2 LDS
#define P2SZ (64*12*12)    // 9216

typedef unsigned short ushort_t;
typedef ushort_t ushort4v __attribute__((ext_vector_type(4)));
typedef short s16x8 __attribute__((ext_vector_type(8)));
typedef float f32x4 __attribute__((ext_vector_type(4)));
typedef float f32x2 __attribute__((ext_vector_type(2)));

__device__ __forceinline__ ushort_t f2bf(float f) {
    union { float f; unsigned u; } a; a.f = f;
    unsigned r = a.u + 0x7FFFu + ((a.u >> 16) & 1u);   // RNE
    return (ushort_t)(r >> 16);
}
__device__ __forceinline__ float bf2f(ushort_t u) {
    union { unsigned u; float f; } a; a.u = ((unsigned)u) << 16;
    return a.f;
}

#define N_WR (64 * 9 * 32)          // 18432
#define N_WF (128 * 9216)           // 1179648
#define CONV1_BLOCKS 3328           // 512*26*2*32 / 256 (13-px half-rows)
#define PREP_BLOCKS  4680           // (N_WR+N_WF)/256

// ---------------- k1: conv1 sliding half-row (packed fp32) + weight prep ----------------
__global__ __launch_bounds__(256) void conv1_prep(const float* __restrict__ x,
                                                  const float* __restrict__ w,
                                                  const float* __restrict__ bias,
                                                  const float* __restrict__ c2w,
                                                  const float* __restrict__ f1w,
                                                  ushort_t* __restrict__ out,
                                                  ushort_t* __restrict__ wr,
                                                  ushort_t* __restrict__ wfb) {
    int blk = blockIdx.x;
    if (blk >= CONV1_BLOCKS) {
        int t = (blk - CONV1_BLOCKS) * 256 + threadIdx.x;
        if (t < N_WR) {
            // conv2 weights: [oc][ic][3][3] f32 -> [oc][tap][ic] bf16
            int ic  = t & 31;
            int tap = (t >> 5) % 9;
            int oc  = t / 288;
            wr[t] = f2bf(c2w[oc * 288 + ic * 9 + tap]);
        } else if (t < N_WR + N_WF) {
            // fc1 weights: K permuted to match channels-last pool2:
            // out k' = pos*64 + oc  <-  in k = oc*144 + pos
            int i  = t - N_WR;
            int oc  = i & 63;
            int pos = (i >> 6) % 144;
            int n   = i / 9216;
            wfb[i] = f2bf(f1w[(size_t)n * 9216 + oc * 144 + pos]);
        }
        return;
    }
    int t = blk * 256 + threadIdx.x;
    int ic = t & 31;
    int r  = t >> 5;
    int h  = r & 1;           // half-row: px0 = 13h
    int r2 = r >> 1;          // b*26 + py
    int py = r2 % 26;
    int b  = r2 / 26;
    int px0 = h * 13;

    const float* wp = w + ic * 9;
    float w00 = wp[0], w01 = wp[1], w02 = wp[2];
    float w10 = wp[3], w11 = wp[4], w12 = wp[5];
    float w20 = wp[6], w21 = wp[7], w22 = wp[8];
    float bv = bias[ic];

    const float* xr = x + b * (54 * 54) + (2 * py) * 54 + 2 * px0;
    ushort_t* po = out + ((size_t)b * POS + py * 26 + px0) * 32 + ic;

    f32x2 p[4], q[4];
#pragma unroll
    for (int rr = 0; rr < 4; ++rr) p[rr] = *reinterpret_cast<const f32x2*>(xr + rr * 54);
#pragma unroll
    for (int rr = 0; rr < 4; ++rr) q[rr] = *reinterpret_cast<const f32x2*>(xr + rr * 54 + 2);

#pragma unroll
    for (int j = 0; j < 13; ++j) {
        f32x2 mid[4];
#pragma unroll
        for (int rr = 0; rr < 4; ++rr) mid[rr] = (f32x2){p[rr].y, q[rr].x};

        f32x2 s0 = p[0] * (f32x2)w00 + mid[0] * (f32x2)w01 + q[0] * (f32x2)w02
                 + p[1] * (f32x2)w10 + mid[1] * (f32x2)w11 + q[1] * (f32x2)w12
                 + p[2] * (f32x2)w20 + mid[2] * (f32x2)w21 + q[2] * (f32x2)w22;
        f32x2 s1 = p[1] * (f32x2)w00 + mid[1] * (f32x2)w01 + q[1] * (f32x2)w02
                 + p[2] * (f32x2)w10 + mid[2] * (f32x2)w11 + q[2] * (f32x2)w12
                 + p[3] * (f32x2)w20 + mid[3] * (f32x2)w21 + q[3] * (f32x2)w22;

        float m = fmaxf(fmaxf(s0.x, s0.y), fmaxf(s1.x, s1.y));
        po[j * 32] = f2bf(fmaxf(m + bv, 0.0f));
        if (j < 12) {
#pragma unroll
            for (int rr = 0; rr < 4; ++rr) {
                p[rr] = q[rr];
                q[rr] = *reinterpret_cast<const f32x2*>(xr + rr * 54 + 2 * j + 4);
            }
        }
    }
}

// ---------------- k2: conv2 MFMA, 3 blocks/image, channels-last epilogue ----------------
__global__ __launch_bounds__(256) void conv2_mfma(const ushort_t* __restrict__ p1,
                                                  const ushort_t* __restrict__ wr,
                                                  const float* __restrict__ bias,
                                                  ushort_t* __restrict__ pool2cl) {
    __shared__ ushort_t lds[260 * ICP];   // 18,720 B
    int blk = blockIdx.x;
    int b = blk / 3, c = blk % 3;
    int tid = threadIdx.x;

    const ushort_t* src = p1 + ((size_t)b * POS + 8 * c * 26) * 32;
    for (int t = tid; t < 260 * 8; t += 256) {
        int pos = t >> 3, off = (t & 7) * 4;
        ushort4v v = *reinterpret_cast<const ushort4v*>(src + pos * 32 + off);
        *reinterpret_cast<ushort4v*>(&lds[pos * ICP + off]) = v;
    }
    __syncthreads();

    int lane = tid & 63, wid = tid >> 6;
    int quad = lane >> 4, lr = lane & 15;

    int ebase[3];
#pragma unroll
    for (int t = 0; t < 3; ++t) {
        int m  = t * 16 + lr;
        int yl = m / 24;
        int xx = m - yl * 24;
        ebase[t] = ((2 * wid + yl) * 26 + xx) * ICP + quad * 8;
    }

    f32x4 acc[3][4];
#pragma unroll
    for (int t = 0; t < 3; ++t)
#pragma unroll
        for (int n = 0; n < 4; ++n) acc[t][n] = (f32x4){0.f, 0.f, 0.f, 0.f};

    const ushort_t* wb = wr + (size_t)lr * 288 + quad * 8;

#pragma unroll
    for (int tap = 0; tap < 9; ++tap) {
        int ky = tap / 3, kx = tap % 3;
        int koff = (ky * 26 + kx) * ICP;
        s16x8 a[3];
#pragma unroll
        for (int t = 0; t < 3; ++t) {
            union { ushort4v s[2]; s16x8 v; } u;
            u.s[0] = *reinterpret_cast<const ushort4v*>(&lds[ebase[t] + koff]);
            u.s[1] = *reinterpret_cast<const ushort4v*>(&lds[ebase[t] + koff + 4]);
            a[t] = u.v;
        }
        s16x8 bf[4];
#pragma unroll
        for (int n = 0; n < 4; ++n)
            bf[n] = *reinterpret_cast<const s16x8*>(wb + n * 4608 + tap * 32);
#pragma unroll
        for (int t = 0; t < 3; ++t)
#pragma unroll
            for (int n = 0; n < 4; ++n)
                acc[t][n] = __builtin_amdgcn_mfma_f32_16x16x32_bf16(a[t], bf[n], acc[t][n], 0, 0, 0);
    }
    __syncthreads();

    // x-pool in regs -> per-wave scratch [wid][oc][i]
    ushort_t* scr = lds + wid * 1536;
#pragma unroll
    for (int t = 0; t < 3; ++t)
#pragma unroll
        for (int n = 0; n < 4; ++n) {
            int oc = n * 16 + lr;
            int i0 = t * 8 + quad * 2;
            float v0 = fmaxf(acc[t][n][0], acc[t][n][1]);
            float v1 = fmaxf(acc[t][n][2], acc[t][n][3]);
            union { ushort_t u2[2]; unsigned w; } pk;
            pk.u2[0] = f2bf(v0); pk.u2[1] = f2bf(v1);
            *reinterpret_cast<unsigned*>(&scr[oc * 24 + i0]) = pk.w;
        }
    // y-pool: lane=oc; channels-last stores: per px, 64 lanes x 2B = 128B contiguous
    int oc = lane;
    const ushort_t* row = scr + oc * 24;
    float bv = bias[oc];
    int py = c * 4 + wid;
    ushort_t* po = pool2cl + ((size_t)b * 144 + py * 12) * 64 + oc;
#pragma unroll
    for (int px = 0; px < 12; ++px) {
        float r0 = bf2f(row[px]);
        float r1 = bf2f(row[px + 12]);
        po[px * 64] = f2bf(fmaxf(fmaxf(r0, r1) + bv, 0.0f));
    }
}

// ---------------- k3: fc1 bf16 MFMA, 32x32-tile waves, permuted K ----------------
// A = pool2cl viewed as [512][9216] with k = pos*64+oc; W = wfb permuted to match.
// wave = 32m x 32n x 288k (9 ksteps, 2A+2B -> 4 MFMA). 2048 waves (8/CU).
__global__ __launch_bounds__(256) void fc1_mfma(const ushort_t* __restrict__ A,
                                                 const ushort_t* __restrict__ W,
                                                 float* __restrict__ Cpart) {
    int tid = threadIdx.x;
    int lane = tid & 63, wid = tid >> 6;
    int lr = lane & 15, quad = lane >> 4;
    int w  = blockIdx.x * 4 + wid;
    int nt = w & 3;
    int ks = (w >> 2) & 31;
    int mt = w >> 7;                 // 0..15

    int m0 = mt * 32;
    int n0 = nt * 32;
    int k0 = ks * 288 + quad * 8;
    const ushort_t* a0 = A + (size_t)(m0 + lr) * 9216 + k0;
    const ushort_t* a1 = a0 + (size_t)16 * 9216;
    const ushort_t* b0 = W + (size_t)(n0 + lr) * 9216 + k0;
    const ushort_t* b1 = b0 + (size_t)16 * 9216;

    f32x4 acc[2][2];
#pragma unroll
    for (int i = 0; i < 2; ++i)
#pragma unroll
        for (int j = 0; j < 2; ++j) acc[i][j] = (f32x4){0.f, 0.f, 0.f, 0.f};

#pragma unroll
    for (int kk = 0; kk < 9; ++kk) {
        s16x8 av0 = *reinterpret_cast<const s16x8*>(a0 + kk * 32);
        s16x8 av1 = *reinterpret_cast<const s16x8*>(a1 + kk * 32);
        s16x8 bv0 = *reinterpret_cast<const s16x8*>(b0 + kk * 32);
        s16x8 bv1 = *reinterpret_cast<const s16x8*>(b1 + kk * 32);
        acc[0][0] = __builtin_amdgcn_mfma_f32_16x16x32_bf16(av0, bv0, acc[0][0], 0, 0, 0);
        acc[0][1] = __builtin_amdgcn_mfma_f32_16x16x32_bf16(av0, bv1, acc[0][1], 0, 0, 0);
        acc[1][0] = __builtin_amdgcn_mfma_f32_16x16x32_bf16(av1, bv0, acc[1][0], 0, 0, 0);
        acc[1][1] = __builtin_amdgcn_mfma_f32_16x16x32_bf16(av1, bv1, acc[1][1], 0, 0, 0);
    }

    float* cp = Cpart + (size_t)ks * (512 * 128);
#pragma unroll
    for (int i = 0; i < 2; ++i) {
        int crow = m0 + i * 16 + quad * 4;
#pragma unroll
        for (int j = 0; j < 2; ++j) {
            int col = n0 + j * 16 + lr;
#pragma unroll
            for (int r = 0; r < 4; ++r)
                cp[(size_t)(crow + r) * 128 + col] = acc[i][j][r];
        }
    }
}

// ---------------- k4: fc1 reduce + bias + relu + fc2 ----------------
__global__ __launch_bounds__(128) void fc1fc2(const float* __restrict__ Cpart,
                                              const float* __restrict__ b1,
                                              const float* __restrict__ w2,
                                              const float* __restrict__ b2,
                                              float* __restrict__ out) {
    __shared__ float h[128];
    int b = blockIdx.x, k = threadIdx.x;
    float s = 0.f;
#pragma unroll
    for (int ks = 0; ks < 32; ++ks) s += Cpart[(size_t)ks * (512 * 128) + b * 128 + k];
    h[k] = fmaxf(s + b1[k], 0.0f);
    __syncthreads();
    if (k < 10) {
        const float* wp = w2 + k * 128;
        float acc = 0.f;
#pragma unroll 8
        for (int j = 0; j < 128; ++j) acc += h[j] * wp[j];
        out[b * 10 + k] = acc + b2[k];
    }
}

extern "C" void kernel_launch(void* const* d_in, const int* in_sizes, int n_in,
                              void* d_out, int out_size, void* d_ws, size_t ws_size,
                              hipStream_t stream) {
    const float* x       = (const float*)d_in[0];
    const float* conv1_w = (const float*)d_in[1];
    const float* conv1_b = (const float*)d_in[2];
    const float* conv2_w = (const float*)d_in[3];
    const float* conv2_b = (const float*)d_in[4];
    const float* fc1_w   = (const float*)d_in[5];
    const float* fc1_b   = (const float*)d_in[6];
    const float* fc2_w   = (const float*)d_in[7];
    const float* fc2_b   = (const float*)d_in[8];
    float* out = (float*)d_out;

    char* ws = (char*)d_ws;
    ushort_t* pool1 = (ushort_t*)ws;                         // 22.1 MB
    ws += (size_t)B * POS * 32 * sizeof(ushort_t);
    ushort_t* wr = (ushort_t*)ws;                            // 36 KB
    ws += N_WR * sizeof(ushort_t) + 128;
    ushort_t* wfb = (ushort_t*)ws;                           // 2.36 MB
    ws += N_WF * sizeof(ushort_t) + 128;
    ushort_t* pool2cl = (ushort_t*)ws;                       // 9.44 MB channels-last
    ws += (size_t)B * P2SZ * sizeof(ushort_t) + 128;
    float* Cpart = (float*)ws;                               // 8.39 MB
    ws += (size_t)32 * 512 * 128 * sizeof(float) + 128;

    {   // k1: conv1 (3328 blocks, 13-px halves) + weight prep (4680 blocks)
        conv1_prep<<<CONV1_BLOCKS + PREP_BLOCKS, 256, 0, stream>>>(
            x, conv1_w, conv1_b, conv2_w, fc1_w, pool1, wr, wfb);
    }
    {   // k2: conv2 MFMA, 3 chunks/image, channels-last out
        conv2_mfma<<<B * 3, 256, 0, stream>>>(pool1, wr, conv2_b, pool2cl);
    }
    {   // k3: fc1 MFMA, 512 blocks (2048 waves)
        fc1_mfma<<<512, 256, 0, stream>>>(pool2cl, wfb, Cpart);
    }
    {   // k4: fc1 reduce + fc2
        fc1fc2<<<B, 128, 0, stream>>>(Cpart, fc1_b, fc2_w, fc2_b, out);
    }
}